// Round 3
// baseline (242.056 us; speedup 1.0000x reference)
//
#include <hip/hip_runtime.h>

// Correlation via banded bf16 MFMA GEMM, v8: barrier-free direct-L2 A-loads.
// out[b, di*21+dj, i, j] = sum_c x1p[b,c,i+di-10,j+dj-10] * x2[b,c,i,j]
//
// Pass 1 (transpose_x1): bf16 channel-contiguous x1 copy in d_ws:
//   x1T[b][r 0..147][col 0..159][c], 16B chunks, chunk = cg (v8: swizzle DROPPED
//   — it existed only for LDS bank conflicts, and pass 2 no longer uses LDS
//   for A; both sides changed together).
// Pass 2 (corr_mfma) v8 REDESIGN: v5/v7 were latency/sync-bound (MfmaUtil 7.5%,
//   VALUBusy 10%, Occupancy 21%): per-step s_barrier lockstep gated on staged
//   LDS arrival. But the per-XCD x1T band (3.4 MB) fits the 4 MB L2, so A-frags
//   are loaded DIRECTLY from global (L2 re-read 573 MB over kernel ≈ 16 TB/s,
//   under the 34.5 TB/s L2 ceiling). This deletes: win[] window, stage_row,
//   and ALL __syncthreads (patch is per-wave; waves fully independent).
//   Occupancy: di split in halves -> 1024 blocks (4/CU demanded); k4-pairwise
//   A loads keep VGPR ~140 -> __launch_bounds__(256,3) = 12 waves/CU resident
//   (up from 8), no spill (v6 lesson: never budget past the allocator cap).
//   LDS = patch only (9,472 B). XCD swizzle kept: L2 residency of the band is
//   now the load-bearing property.

#define NB 4
#define NC 128
#define NW 128
#define NH 128
#define DW 21
#define PAD 10
#define NROW_T 148   // NW + 2*PAD
#define NCOL_T 160   // padded cols (148..159 zero)
#define NCH 441
#define PS 37        // patch col stride (col-major [16 cols][37 rows]); 0 conflicts measured
#define ROW_US (NCOL_T * NC)    // 20480 ushorts per full x1T row

typedef __attribute__((ext_vector_type(8))) short short8;   // 8 bf16
typedef __attribute__((ext_vector_type(4))) float float4v;  // 4 fp32

__device__ inline ushort f2bf(float f) {
    union { float f; uint u; } v; v.f = f;
    const uint u = v.u;
    return (ushort)((u + 0x7fffu + ((u >> 16) & 1u)) >> 16);  // RNE
}

// One block per (b, padded row r). Identical to v5 except chunk = cg (no XOR).
__global__ __launch_bounds__(256) void transpose_x1(const float* __restrict__ x1,
                                                    ushort* __restrict__ x1T) {
    __shared__ uint tile[128][65];
    const int t = threadIdx.x;
    const int b = blockIdx.x / NROW_T;
    const int r = blockIdx.x % NROW_T;
    const int w = r - PAD;
    const bool inr = (w >= 0 && w < NW);
    if (inr) {
        #pragma unroll
        for (int it = 0; it < 8; ++it) {
            const int u = it * 256 + t;
            const int g4 = u & 31;          // float4 group along h (coalesced)
            const int cp = u >> 5;          // channel pair
            const float4 va = *(const float4*)&x1[(((size_t)b * NC + 2 * cp    ) * NW + w) * NH + g4 * 4];
            const float4 vb = *(const float4*)&x1[(((size_t)b * NC + 2 * cp + 1) * NW + w) * NH + g4 * 4];
            tile[g4 * 4 + 0][cp] = (uint)f2bf(va.x) | ((uint)f2bf(vb.x) << 16);
            tile[g4 * 4 + 1][cp] = (uint)f2bf(va.y) | ((uint)f2bf(vb.y) << 16);
            tile[g4 * 4 + 2][cp] = (uint)f2bf(va.z) | ((uint)f2bf(vb.z) << 16);
            tile[g4 * 4 + 3][cp] = (uint)f2bf(va.w) | ((uint)f2bf(vb.w) << 16);
        }
    }
    __syncthreads();
    #pragma unroll
    for (int it = 0; it < 10; ++it) {
        const int u = it * 256 + t;
        const int cg = u & 15;
        const int col = u >> 4;             // 0..159
        uint4 v = make_uint4(0, 0, 0, 0);
        const int h = col - PAD;
        if (inr && h >= 0 && h < NH) {
            v.x = tile[h][cg * 4 + 0];
            v.y = tile[h][cg * 4 + 1];
            v.z = tile[h][cg * 4 + 2];
            v.w = tile[h][cg * 4 + 3];
        }
        // v8: plain chunk order (corr reads chunk = kc directly from global)
        *(uint4*)&x1T[(((size_t)b * NROW_T + r) * NCOL_T + col) * NC + cg * 8] = v;
    }
}

// Block = (b, i-quad, j-quarter, di-half), XCD-swizzled. 256 threads = 4 waves
// = 4 output rows. No LDS window, no barriers: each wave streams its A-row
// fragments straight from (L2-resident) x1T each step.
__global__ __launch_bounds__(256, 3) void corr_mfma(const ushort* __restrict__ x1T,
                                                    const float* __restrict__ x2,
                                                    float* __restrict__ out) {
    __shared__ float patch[4][16 * PS];     // 9,472 B — the only LDS

    const int t = threadIdx.x;
    const int wave = t >> 6;                // = row offset 0..3
    const int lane = t & 63;
    const int n16 = lane & 15;
    const int q = lane >> 4;

    // XCD swizzle: hw XCD = blockIdx%8 -> XCD k serves (b = k>>1, ihalf = k&1);
    // per-XCD x1T band ~3.4 MB < 4 MB L2. 128 slots = 16 i-quads x 4 j-quarters
    // x 2 di-halves (di-halves adjacent -> co-scheduled -> share x2 in L2).
    const int n = blockIdx.x;
    const int b = (n & 7) >> 1;
    const int ihalf = n & 1;
    const int slot = n >> 3;                // 0..127
    const int dihalf = slot & 1;
    const int jq = (slot >> 1) & 3;
    const int iq = ihalf * 16 + (slot >> 3);
    const int i0 = iq * 4;
    const int col0 = jq * 32;
    const int i = i0 + wave;
    const int di0 = dihalf ? 11 : 0;
    const int diN = dihalf ? 21 : 11;

    // B fragments from fp32 x2 (read once per block; lane n=n16, k=q*8+e+32*k4)
    short8 Bf[2][4];
    #pragma unroll
    for (int nt = 0; nt < 2; ++nt) {
        const int jc = col0 + nt * 16 + n16;
        #pragma unroll
        for (int k4 = 0; k4 < 4; ++k4) {
            short8 s;
            #pragma unroll
            for (int e = 0; e < 8; ++e) {
                const int c = k4 * 32 + q * 8 + e;
                s[e] = (short)f2bf(x2[(((size_t)b * NC + c) * NW + i) * NH + jc]);
            }
            Bf[nt][k4] = s;
        }
    }

    float* P = &patch[wave][0];
    const ushort* Abase = x1T + ((size_t)(b * NROW_T) * NCOL_T + col0) * NC;

    for (int di = di0; di < diN; ++di) {
        // wave's A-row = i0 + wave + di (<= 147), direct from global/L2.
        const ushort* A = Abase + (size_t)(i0 + wave + di) * ROW_US;

        float4v a00 = {0.f,0.f,0.f,0.f}, a01 = {0.f,0.f,0.f,0.f}, a02 = {0.f,0.f,0.f,0.f};
        float4v a10 = {0.f,0.f,0.f,0.f}, a11 = {0.f,0.f,0.f,0.f}, a12 = {0.f,0.f,0.f,0.f};

        // k4-pairwise A loads (8 frags = 32 VGPR live) keep total VGPR ~140.
        #pragma unroll
        for (int kh = 0; kh < 2; ++kh) {
            short8 Ah[4][2];
            #pragma unroll
            for (int tl = 0; tl < 4; ++tl) {
                const int base = (tl < 3) ? tl * 16 : 36;   // col tiles {0,16,32,36}
                #pragma unroll
                for (int j = 0; j < 2; ++j) {
                    const int k4 = kh * 2 + j;
                    Ah[tl][j] = *(const short8*)&A[(base + n16) * NC + (q + 4 * k4) * 8];
                }
            }
            #pragma unroll
            for (int j = 0; j < 2; ++j) {
                const int k4 = kh * 2 + j;
                a00 = __builtin_amdgcn_mfma_f32_16x16x32_bf16(Ah[0][j], Bf[0][k4], a00, 0, 0, 0);
                a01 = __builtin_amdgcn_mfma_f32_16x16x32_bf16(Ah[1][j], Bf[0][k4], a01, 0, 0, 0);
                a02 = __builtin_amdgcn_mfma_f32_16x16x32_bf16(Ah[2][j], Bf[0][k4], a02, 0, 0, 0);
                a10 = __builtin_amdgcn_mfma_f32_16x16x32_bf16(Ah[1][j], Bf[1][k4], a10, 0, 0, 0);
                a11 = __builtin_amdgcn_mfma_f32_16x16x32_bf16(Ah[2][j], Bf[1][k4], a11, 0, 0, 0);
                a12 = __builtin_amdgcn_mfma_f32_16x16x32_bf16(Ah[3][j], Bf[1][k4], a12, 0, 0, 0);
            }
        }

        // Epilogue: per nt, band-extract via per-wave col-major patch P[n*37 + r].
        // Per-wave private patch + in-wave program order -> no barriers needed.
        #pragma unroll
        for (int nt = 0; nt < 2; ++nt) {
            const float4v va = nt ? a10 : a00;  // rel rows 0..15
            const float4v vb = nt ? a11 : a01;  // rel rows 16..31
            const float4v vc = nt ? a12 : a02;  // nt0 q==0 / nt1 q==3 -> rows 32..35
            #pragma unroll
            for (int reg = 0; reg < 4; ++reg) {
                P[n16 * PS + q * 4 + reg]      = va[reg];
                P[n16 * PS + 16 + q * 4 + reg] = vb[reg];
            }
            if (q == (nt ? 3 : 0)) {
                #pragma unroll
                for (int reg = 0; reg < 4; ++reg)
                    P[n16 * PS + 32 + reg] = vc[reg];
            }
            #pragma unroll
            for (int it2 = 0; it2 < 2; ++it2) {
                const int u = it2 * 64 + lane;
                if (u < 84) {
                    const int dj = u >> 2;
                    const int jj = (u & 3) * 4;
                    float4v v;
                    #pragma unroll
                    for (int p = 0; p < 4; ++p)
                        v[p] = P[(jj + p) * (PS + 1) + dj];  // col jj+p, row jj+p+dj
                    *(float4v*)&out[(((size_t)(b * NCH + di * DW + dj)) * NW + i) * NH
                                    + col0 + nt * 16 + jj] = v;
                }
            }
        }
    }
}

extern "C" void kernel_launch(void* const* d_in, const int* in_sizes, int n_in,
                              void* d_out, int out_size, void* d_ws, size_t ws_size,
                              hipStream_t stream) {
    const float* x1 = (const float*)d_in[0];
    const float* x2 = (const float*)d_in[1];
    float* out = (float*)d_out;
    ushort* x1T = (ushort*)d_ws;  // 4*148*160*128*2 = 24,248,320 B
    transpose_x1<<<dim3(NB * NROW_T), dim3(256), 0, stream>>>(x1, x1T);
    corr_mfma<<<dim3(NB * 32 * 4 * 2), dim3(256), 0, stream>>>(x1T, x2, out);
}

// Round 4
// 233.923 us; speedup vs baseline: 1.0348x; 1.0348x over previous
//
#include <hip/hip_runtime.h>

// Correlation via banded bf16 MFMA GEMM, v9: barrier-free corr with 2-deep
// A-fragment register pipeline + higher-parallelism transpose.
// out[b, di*21+dj, i, j] = sum_c x1p[b,c,i+di-10,j+dj-10] * x2[b,c,i,j]
//
// Pass 1 (transpose_x1) v9: split over channel-halves -> grid 1184 (was 592),
//   LDS tile halved to 16.9 KB, 18.5 waves/CU (was 9.25). Plain chunk order
//   (no XOR swizzle; pass 2 reads straight from global, both sides plain).
// Pass 2 (corr_mfma) v9: v8 was latency-bound (MfmaUtil 5.7%, VALUBusy 3.9%,
//   HBM 18% -- all idle): no prefetch meant each step serialized
//   [16 L2 loads -> MFMA -> epilogue]. Fix: register double-buffer AfX/AfY,
//   modulo-2 unrolled pipeline (static indexing, no scratch):
//     load(next) issued BEFORE compute(cur) -> every load set gets a full
//     compute phase (~500 cyc) of slack > L2 latency (~200-400 cyc).
//   No LDS staging, no barriers (patch is per-wave). 512 blocks = 2/CU
//   co-resident, 8 waves/CU. __launch_bounds__(256,2): VGPR budget
//   128(A) + 32(B) + 24(acc->AGPR) + misc ~= 210 < 256, no spill.
//   XCD swizzle kept: per-XCD x1T band ~3.4 MB stays L2-resident (the
//   load-bearing property for cheap A re-reads).

#define NB 4
#define NC 128
#define NW 128
#define NH 128
#define DW 21
#define PAD 10
#define NROW_T 148   // NW + 2*PAD
#define NCOL_T 160   // padded cols (148..159 zero)
#define NCH 441
#define PS 37        // patch col stride (col-major [16 cols][37 rows]); ~2% conflict cost
#define ROW_US (NCOL_T * NC)    // 20480 ushorts per full x1T row

typedef __attribute__((ext_vector_type(8))) short short8;   // 8 bf16
typedef __attribute__((ext_vector_type(4))) float float4v;  // 4 fp32

__device__ inline ushort f2bf(float f) {
    union { float f; uint u; } v; v.f = f;
    const uint u = v.u;
    return (ushort)((u + 0x7fffu + ((u >> 16) & 1u)) >> 16);  // RNE
}

__device__ inline uint packbf(float a, float b) {
    return (uint)f2bf(a) | ((uint)f2bf(b) << 16);
}

// One block per (b, padded row r, channel-half). Grid 1184 = 4.6 blocks/CU
// (v8: 592 = 2.3/CU) -> 2x memory-level parallelism for the HBM reads.
__global__ __launch_bounds__(256) void transpose_x1(const float* __restrict__ x1,
                                                    ushort* __restrict__ x1T) {
    __shared__ uint tile[128][33];          // [h][channel-pair], 16,896 B
    const int t = threadIdx.x;
    const int bid = blockIdx.x;
    const int chalf = bid & 1;
    const int r = (bid >> 1) % NROW_T;
    const int b = (bid >> 1) / NROW_T;
    const int w = r - PAD;
    const bool inr = (w >= 0 && w < NW);
    if (inr) {
        #pragma unroll
        for (int it = 0; it < 4; ++it) {
            const int u = it * 256 + t;
            const int g4 = u & 31;          // float4 group along h (coalesced)
            const int cp = u >> 5;          // channel pair within half (0..31)
            const int c = chalf * 64 + 2 * cp;
            const float4 va = *(const float4*)&x1[(((size_t)b * NC + c    ) * NW + w) * NH + g4 * 4];
            const float4 vb = *(const float4*)&x1[(((size_t)b * NC + c + 1) * NW + w) * NH + g4 * 4];
            tile[g4 * 4 + 0][cp] = packbf(va.x, vb.x);
            tile[g4 * 4 + 1][cp] = packbf(va.y, vb.y);
            tile[g4 * 4 + 2][cp] = packbf(va.z, vb.z);
            tile[g4 * 4 + 3][cp] = packbf(va.w, vb.w);
        }
    }
    __syncthreads();
    #pragma unroll
    for (int it = 0; it < 5; ++it) {
        const int u = it * 256 + t;
        const int cg = u & 7;               // chunk within half (0..7)
        const int col = u >> 3;             // 0..159
        uint4 v = make_uint4(0, 0, 0, 0);
        const int h = col - PAD;
        if (inr && h >= 0 && h < NH) {
            v.x = tile[h][cg * 4 + 0];
            v.y = tile[h][cg * 4 + 1];
            v.z = tile[h][cg * 4 + 2];
            v.w = tile[h][cg * 4 + 3];
        }
        *(uint4*)&x1T[(((size_t)b * NROW_T + r) * NCOL_T + col) * NC
                      + (chalf * 8 + cg) * 8] = v;
    }
}

// 16 x 16B A-fragment loads for one di, straight from (L2-resident) x1T.
// Layout is fragment-ready: frag = 16B contiguous chunk at [(col)*NC + k4*32+q*8].
__device__ __forceinline__ void loadA(short8 (&buf)[4][4], const ushort* Ap,
                                      int n16, int q) {
    #pragma unroll
    for (int tl = 0; tl < 4; ++tl) {
        const int base = (tl < 3) ? tl * 16 : 36;   // col tiles {0,16,32,36}
        #pragma unroll
        for (int k4 = 0; k4 < 4; ++k4)
            buf[tl][k4] = *(const short8*)&Ap[(base + n16) * NC + (q + 4 * k4) * 8];
    }
}

// 24 MFMA + band-extract epilogue for one di. Per-wave private patch ->
// in-wave program order is the only sync needed.
__device__ __forceinline__ void computeStep(const short8 (&Af)[4][4],
                                            const short8 (&Bf)[2][4],
                                            float* P, float* __restrict__ out,
                                            int b, int di, int i, int col0,
                                            int n16, int q, int lane) {
    float4v a00 = {0.f,0.f,0.f,0.f}, a01 = {0.f,0.f,0.f,0.f}, a02 = {0.f,0.f,0.f,0.f};
    float4v a10 = {0.f,0.f,0.f,0.f}, a11 = {0.f,0.f,0.f,0.f}, a12 = {0.f,0.f,0.f,0.f};
    #pragma unroll
    for (int k4 = 0; k4 < 4; ++k4) {
        a00 = __builtin_amdgcn_mfma_f32_16x16x32_bf16(Af[0][k4], Bf[0][k4], a00, 0, 0, 0);
        a01 = __builtin_amdgcn_mfma_f32_16x16x32_bf16(Af[1][k4], Bf[0][k4], a01, 0, 0, 0);
        a02 = __builtin_amdgcn_mfma_f32_16x16x32_bf16(Af[2][k4], Bf[0][k4], a02, 0, 0, 0);
        a10 = __builtin_amdgcn_mfma_f32_16x16x32_bf16(Af[1][k4], Bf[1][k4], a10, 0, 0, 0);
        a11 = __builtin_amdgcn_mfma_f32_16x16x32_bf16(Af[2][k4], Bf[1][k4], a11, 0, 0, 0);
        a12 = __builtin_amdgcn_mfma_f32_16x16x32_bf16(Af[3][k4], Bf[1][k4], a12, 0, 0, 0);
    }
    #pragma unroll
    for (int nt = 0; nt < 2; ++nt) {
        const float4v va = nt ? a10 : a00;  // rel rows 0..15
        const float4v vb = nt ? a11 : a01;  // rel rows 16..31
        const float4v vc = nt ? a12 : a02;  // nt0 q==0 / nt1 q==3 -> rows 32..35
        #pragma unroll
        for (int reg = 0; reg < 4; ++reg) {
            P[n16 * PS + q * 4 + reg]      = va[reg];
            P[n16 * PS + 16 + q * 4 + reg] = vb[reg];
        }
        if (q == (nt ? 3 : 0)) {
            #pragma unroll
            for (int reg = 0; reg < 4; ++reg)
                P[n16 * PS + 32 + reg] = vc[reg];
        }
        #pragma unroll
        for (int it2 = 0; it2 < 2; ++it2) {
            const int u = it2 * 64 + lane;
            if (u < 84) {
                const int dj = u >> 2;
                const int jj = (u & 3) * 4;
                float4v v;
                #pragma unroll
                for (int p = 0; p < 4; ++p)
                    v[p] = P[(jj + p) * (PS + 1) + dj];  // col jj+p, row jj+p+dj
                *(float4v*)&out[(((size_t)(b * NCH + di * DW + dj)) * NW + i) * NH
                                + col0 + nt * 16 + jj] = v;
            }
        }
    }
}

// Block = (b, i-quad, j-quarter), XCD-swizzled, 512 blocks = 2/CU co-resident.
// 256 threads = 4 waves = 4 output rows; each wave streams A-rows i0+wave+di
// through a 2-deep register pipeline. No LDS staging, no barriers.
__global__ __launch_bounds__(256, 2) void corr_mfma(const ushort* __restrict__ x1T,
                                                    const float* __restrict__ x2,
                                                    float* __restrict__ out) {
    __shared__ float patch[4][16 * PS];     // 9,472 B — the only LDS

    const int t = threadIdx.x;
    const int wave = t >> 6;                // = row offset 0..3
    const int lane = t & 63;
    const int n16 = lane & 15;
    const int q = lane >> 4;

    // XCD swizzle: hw XCD = blockIdx%8 -> XCD k serves (b = k>>1, ihalf = k&1);
    // per-XCD x1T band ~3.4 MB < 4 MB L2. 64 slots = 16 i-quads x 4 j-quarters.
    const int n = blockIdx.x;
    const int b = (n & 7) >> 1;
    const int ihalf = n & 1;
    const int slot = n >> 3;                // 0..63
    const int iq = ihalf * 16 + (slot >> 2);
    const int jq = slot & 3;
    const int i0 = iq * 4;
    const int col0 = jq * 32;
    const int i = i0 + wave;

    // B fragments from fp32 x2 (read once per block; lane n=n16, k=q*8+e+32*k4)
    short8 Bf[2][4];
    #pragma unroll
    for (int nt = 0; nt < 2; ++nt) {
        const int jc = col0 + nt * 16 + n16;
        #pragma unroll
        for (int k4 = 0; k4 < 4; ++k4) {
            short8 s;
            #pragma unroll
            for (int e = 0; e < 8; ++e) {
                const int c = k4 * 32 + q * 8 + e;
                s[e] = (short)f2bf(x2[(((size_t)b * NC + c) * NW + i) * NH + jc]);
            }
            Bf[nt][k4] = s;
        }
    }

    float* P = &patch[wave][0];
    const ushort* Abase = x1T + ((size_t)(b * NROW_T) * NCOL_T + col0) * NC
                        + (size_t)(i0 + wave) * ROW_US;

    // 2-deep modulo-2 register pipeline over di = 0..20 (all rows <= 147).
    // Static buffer naming (AfX/AfY) keeps every access compile-time-indexed.
    short8 AfX[4][4], AfY[4][4];
    loadA(AfX, Abase, n16, q);                                   // di = 0
    for (int ss = 0; ss < 10; ++ss) {
        const int di0 = 2 * ss;
        loadA(AfY, Abase + (size_t)(di0 + 1) * ROW_US, n16, q);  // next
        computeStep(AfX, Bf, P, out, b, di0, i, col0, n16, q, lane);
        loadA(AfX, Abase + (size_t)(di0 + 2) * ROW_US, n16, q);  // next-next
        computeStep(AfY, Bf, P, out, b, di0 + 1, i, col0, n16, q, lane);
    }
    computeStep(AfX, Bf, P, out, b, 20, i, col0, n16, q, lane);  // di = 20
}

extern "C" void kernel_launch(void* const* d_in, const int* in_sizes, int n_in,
                              void* d_out, int out_size, void* d_ws, size_t ws_size,
                              hipStream_t stream) {
    const float* x1 = (const float*)d_in[0];
    const float* x2 = (const float*)d_in[1];
    float* out = (float*)d_out;
    ushort* x1T = (ushort*)d_ws;  // 4*148*160*128*2 = 24,248,320 B
    transpose_x1<<<dim3(NB * NROW_T * 2), dim3(256), 0, stream>>>(x1, x1T);
    corr_mfma<<<dim3(NB * 32 * 4), dim3(256), 0, stream>>>(x1T, x2, out);
}

// Round 5
// 193.441 us; speedup vs baseline: 1.2513x; 1.2093x over previous
//
#include <hip/hip_runtime.h>

// Correlation via banded bf16 MFMA GEMM, v10: v5 staging structure with
// same-row wave mapping -> 3-buffer window -> 3 blocks/CU.
// out[b, di*21+dj, i, j] = sum_c x1p[b,c,i+di-10,j+dj-10] * x2[b,c,i,j]
//
// Pass 1 (transpose_x1): v5 verbatim (best measured "rest" = ~52 us):
//   x1T[b][r 0..147][col 0..159][c], 16B chunks XOR-swizzled chunk' = cg ^ (col&15).
// Pass 2 (corr_mfma) v10: history: v5 (65us) = LDS staging + per-step barrier,
//   2 blocks/CU; v7 counted-vmcnt = neutral (stall isn't store drain); v8/v9
//   direct-L2 A-loads = 100-110us (L2 traffic x5 + latency exposed). So keep
//   v5's staging (minimal L2 traffic, global_load_lds) and attack the real
//   limiter: nothing to overlap the lockstep staging stall at 2 blocks/CU.
//   CHANGE: all 4 waves consume the SAME staged row each step s (row i0+s);
//   wave w computes di = s - w for its own output row i = i0 + w. Live rows:
//   current + 2 prefetch = 3 buffers (v5 needed 5: 4-row spread + prefetch).
//   LDS 76 -> 49.4 KB -> 3 blocks/CU. Bf stays per-wave own-row (32 VGPR;
//   avoids v6's x4 x2-read blowup). Grid 512 -> 1024 via di-halves so 3/CU
//   is populated (di 0..10 / 11..20; steps s = w..w+? gated per wave).
//   Per-step cost otherwise identical to v5. __launch_bounds__(256,3)
//   (VGPR cap 170; budget Af64+Bf32+acc24+misc ~ 140).

#define NB 4
#define NC 128
#define NW 128
#define NH 128
#define DW 21
#define PAD 10
#define NROW_T 148   // NW + 2*PAD
#define NCOL_T 160   // padded cols (148..159 zero)
#define NCH 441
#define PS 37        // patch col stride (col-major [16 cols][37 rows]); 0-conflict measured
#define SCOLS 52     // slice cols: 32 out + 20 halo
#define SUS (SCOLS * NC)        // 6656 ushorts = 13,312 B
#define ROW_US (NCOL_T * NC)    // 20480 ushorts per full x1T row
#define NBUF 3

typedef __attribute__((ext_vector_type(8))) short short8;   // 8 bf16
typedef __attribute__((ext_vector_type(4))) float float4v;  // 4 fp32

__device__ inline ushort f2bf(float f) {
    union { float f; uint u; } v; v.f = f;
    const uint u = v.u;
    return (ushort)((u + 0x7fffu + ((u >> 16) & 1u)) >> 16);  // RNE
}

__device__ inline void async_copy16(const void* g, void* l) {
    __builtin_amdgcn_global_load_lds(
        (const __attribute__((address_space(1))) void*)g,
        (__attribute__((address_space(3))) void*)l, 16, 0, 0);
}

// Stage one 13,312 B row slice: 3 full 4 KB rounds + 1 KB tail (wave 0 only).
__device__ inline void stage_row(const ushort* src, ushort* dst, int t) {
    const char* s = (const char*)src;
    char* d = (char*)dst;
    #pragma unroll
    for (int it = 0; it < 3; ++it) {
        const int off = it * 4096 + t * 16;
        async_copy16(s + off, d + off);
    }
    if (t < 64) {
        const int off = 12288 + t * 16;
        async_copy16(s + off, d + off);
    }
}

// One block per (b, padded row r). v5 verbatim.
__global__ __launch_bounds__(256) void transpose_x1(const float* __restrict__ x1,
                                                    ushort* __restrict__ x1T) {
    __shared__ uint tile[128][65];
    const int t = threadIdx.x;
    const int b = blockIdx.x / NROW_T;
    const int r = blockIdx.x % NROW_T;
    const int w = r - PAD;
    const bool inr = (w >= 0 && w < NW);
    if (inr) {
        #pragma unroll
        for (int it = 0; it < 8; ++it) {
            const int u = it * 256 + t;
            const int g4 = u & 31;          // float4 group along h (coalesced)
            const int cp = u >> 5;          // channel pair
            const float4 va = *(const float4*)&x1[(((size_t)b * NC + 2 * cp    ) * NW + w) * NH + g4 * 4];
            const float4 vb = *(const float4*)&x1[(((size_t)b * NC + 2 * cp + 1) * NW + w) * NH + g4 * 4];
            tile[g4 * 4 + 0][cp] = (uint)f2bf(va.x) | ((uint)f2bf(vb.x) << 16);
            tile[g4 * 4 + 1][cp] = (uint)f2bf(va.y) | ((uint)f2bf(vb.y) << 16);
            tile[g4 * 4 + 2][cp] = (uint)f2bf(va.z) | ((uint)f2bf(vb.z) << 16);
            tile[g4 * 4 + 3][cp] = (uint)f2bf(va.w) | ((uint)f2bf(vb.w) << 16);
        }
    }
    __syncthreads();
    #pragma unroll
    for (int it = 0; it < 10; ++it) {
        const int u = it * 256 + t;
        const int cg = u & 15;
        const int col = u >> 4;             // 0..159
        uint4 v = make_uint4(0, 0, 0, 0);
        const int h = col - PAD;
        if (inr && h >= 0 && h < NH) {
            v.x = tile[h][cg * 4 + 0];
            v.y = tile[h][cg * 4 + 1];
            v.z = tile[h][cg * 4 + 2];
            v.w = tile[h][cg * 4 + 3];
        }
        const int chunk = cg ^ (col & 15);  // swizzle for conflict-free pass-2 reads
        *(uint4*)&x1T[(((size_t)b * NROW_T + r) * NCOL_T + col) * NC + chunk * 8] = v;
    }
}

// Block = (b, i-quad, j-quarter, di-half), XCD-swizzled, 1024 blocks,
// 3 blocks/CU (LDS 49.4 KB). 4 waves all read the same staged row per step.
__global__ __launch_bounds__(256, 3) void corr_mfma(const ushort* __restrict__ x1T,
                                                    const float* __restrict__ x2,
                                                    float* __restrict__ out) {
    __shared__ ushort win[NBUF][SUS];       // 39,936 B rolling row window
    __shared__ float patch[4][16 * PS];     // 9,472 B

    const int t = threadIdx.x;
    const int wave = t >> 6;
    const int lane = t & 63;
    const int n16 = lane & 15;
    const int q = lane >> 4;

    // XCD swizzle: hw XCD = blockIdx%8 -> XCD k serves (b = k>>1, ihalf = k&1);
    // per-XCD x1T band ~3.4 MB < 4 MB L2. 128 slots = 16 iq x 4 jq x 2 di-halves
    // (di-halves adjacent -> co-scheduled -> share x2/x1T in L2).
    const int n = blockIdx.x;
    const int b = (n & 7) >> 1;
    const int ihalf = n & 1;
    const int slot = n >> 3;                // 0..127
    const int dihalf = slot & 1;
    const int jq = (slot >> 1) & 3;
    const int iq = ihalf * 16 + (slot >> 3);
    const int i0 = iq * 4;
    const int col0 = jq * 32;
    const int i = i0 + wave;                // this wave's output row

    const int s0    = dihalf ? 11 : 0;      // first staged-row offset
    const int s_end = dihalf ? 23 : 13;     // last staged-row offset (inclusive)
    const int dlo   = dihalf ? 11 : 0;      // valid di range for this block
    const int dhi   = dihalf ? 20 : 10;

    const ushort* xbase = x1T + (size_t)(b * NROW_T + i0) * ROW_US + (size_t)col0 * NC;

    // prologue: stage rows s0, s0+1 into buffers s0%3, (s0+1)%3
    stage_row(xbase + (size_t)s0 * ROW_US, win[s0 % NBUF], t);
    stage_row(xbase + (size_t)(s0 + 1) * ROW_US, win[(s0 + 1) % NBUF], t);

    // B fragments from fp32 x2 (own row only; lane n=n16, k=q*8+e+32*k4)
    short8 Bf[2][4];
    #pragma unroll
    for (int nt = 0; nt < 2; ++nt) {
        const int jc = col0 + nt * 16 + n16;
        #pragma unroll
        for (int k4 = 0; k4 < 4; ++k4) {
            short8 s;
            #pragma unroll
            for (int e = 0; e < 8; ++e) {
                const int c = k4 * 32 + q * 8 + e;
                s[e] = (short)f2bf(x2[(((size_t)b * NC + c) * NW + i) * NH + jc]);
            }
            Bf[nt][k4] = s;
        }
    }

    __syncthreads();  // prologue staging + B loads drained

    float* P = &patch[wave][0];

    for (int s = s0; s <= s_end; ++s) {
        const int di = s - wave;            // this wave's di at step s
        const bool act = (di >= dlo) && (di <= dhi);  // wave-uniform gate

        // A-frag ds_reads first (only active waves; same row for all waves)
        short8 Af[4][4];
        if (act) {
            const ushort* A = win[s % NBUF];
            #pragma unroll
            for (int k4 = 0; k4 < 4; ++k4) {
                const int kc = q + 4 * k4;
                #pragma unroll
                for (int tl = 0; tl < 4; ++tl) {
                    const int base = (tl < 3) ? tl * 16 : 36;
                    const int c = base + n16;
                    Af[tl][k4] = *(const short8*)&A[c * NC + ((kc ^ (c & 15)) & 15) * 8];
                }
            }
        }

        // prefetch row s+2 into buffer (s+2)%3 (block-uniform; 2 steps of slack)
        if (s + 2 <= s_end)
            stage_row(xbase + (size_t)(s + 2) * ROW_US, win[(s + 2) % NBUF], t);

        if (act) {
            float4v a00 = {0.f,0.f,0.f,0.f}, a01 = {0.f,0.f,0.f,0.f}, a02 = {0.f,0.f,0.f,0.f};
            float4v a10 = {0.f,0.f,0.f,0.f}, a11 = {0.f,0.f,0.f,0.f}, a12 = {0.f,0.f,0.f,0.f};
            #pragma unroll
            for (int k4 = 0; k4 < 4; ++k4) {
                a00 = __builtin_amdgcn_mfma_f32_16x16x32_bf16(Af[0][k4], Bf[0][k4], a00, 0, 0, 0);
                a01 = __builtin_amdgcn_mfma_f32_16x16x32_bf16(Af[1][k4], Bf[0][k4], a01, 0, 0, 0);
                a02 = __builtin_amdgcn_mfma_f32_16x16x32_bf16(Af[2][k4], Bf[0][k4], a02, 0, 0, 0);
                a10 = __builtin_amdgcn_mfma_f32_16x16x32_bf16(Af[1][k4], Bf[1][k4], a10, 0, 0, 0);
                a11 = __builtin_amdgcn_mfma_f32_16x16x32_bf16(Af[2][k4], Bf[1][k4], a11, 0, 0, 0);
                a12 = __builtin_amdgcn_mfma_f32_16x16x32_bf16(Af[3][k4], Bf[1][k4], a12, 0, 0, 0);
            }

            // Epilogue: per nt, band-extract via per-wave col-major patch P[n*37 + r].
            #pragma unroll
            for (int nt = 0; nt < 2; ++nt) {
                const float4v va = nt ? a10 : a00;  // rel rows 0..15
                const float4v vb = nt ? a11 : a01;  // rel rows 16..31
                const float4v vc = nt ? a12 : a02;  // nt0 q==0 / nt1 q==3 -> rows 32..35
                #pragma unroll
                for (int reg = 0; reg < 4; ++reg) {
                    P[n16 * PS + q * 4 + reg]      = va[reg];
                    P[n16 * PS + 16 + q * 4 + reg] = vb[reg];
                }
                if (q == (nt ? 3 : 0)) {
                    #pragma unroll
                    for (int reg = 0; reg < 4; ++reg)
                        P[n16 * PS + 32 + reg] = vc[reg];
                }
                #pragma unroll
                for (int it2 = 0; it2 < 2; ++it2) {
                    const int u = it2 * 64 + lane;
                    if (u < 84) {
                        const int dj = u >> 2;
                        const int jj = (u & 3) * 4;
                        float4v v;
                        #pragma unroll
                        for (int p = 0; p < 4; ++p)
                            v[p] = P[(jj + p) * (PS + 1) + dj];  // col jj+p, row jj+p+dj
                        *(float4v*)&out[(((size_t)(b * NCH + di * DW + dj)) * NW + i) * NH
                                        + col0 + nt * 16 + jj] = v;
                    }
                }
            }
        }

        __syncthreads();  // window rotation: staged buffer ready / read buffer free
    }
}

extern "C" void kernel_launch(void* const* d_in, const int* in_sizes, int n_in,
                              void* d_out, int out_size, void* d_ws, size_t ws_size,
                              hipStream_t stream) {
    const float* x1 = (const float*)d_in[0];
    const float* x2 = (const float*)d_in[1];
    float* out = (float*)d_out;
    ushort* x1T = (ushort*)d_ws;  // 4*148*160*128*2 = 24,248,320 B
    transpose_x1<<<dim3(NB * NROW_T), dim3(256), 0, stream>>>(x1, x1T);
    corr_mfma<<<dim3(NB * 32 * 4 * 2), dim3(256), 0, stream>>>(x1T, x2, out);
}

// Round 6
// 191.584 us; speedup vs baseline: 1.2634x; 1.0097x over previous
//
#include <hip/hip_runtime.h>

// Correlation via banded bf16 MFMA GEMM, v11: v5 staging + same-row WRAPAROUND
// mapping -> 3 buffers with TWO-step prefetch depth + counted-vmcnt barrier.
// out[b, di*21+dj, i, j] = sum_c x1p[b,c,i+di-10,j+dj-10] * x2[b,c,i,j]
//
// Pass 1 (transpose_x1): v5 verbatim (do not touch without counters; v9's
//   channel-half split regressed via 128B half-line writes).
// Pass 2 (corr_mfma): evidence: v7 (counted vmcnt over stores) null ->
//   the per-step stall is the STAGING arrival: v5 stages row di+4 at step di,
//   wave 3 reads it at step di+1 -> 1-step deadline; the barrier eats the
//   remaining DMA latency every step. v5 can't deepen prefetch (rows consumed
//   4-abreast: +1 depth = +13.3KB; 6 bufs -> 1 block/CU).
//   FIX: wave w at step s computes di = (s-w) mod 21 for its FIXED output row
//   i = i0+w. For s >= w all waves read the SAME staged row i0+s -> rows are
//   consumed 1/step -> 3 buffers give depth-2 (stage s+2 at step s, read at
//   s+2: ~2 steps of lead >> L2 latency). All waves active every step (no v10
//   gating waste); 21 steps; ds_reads/swizzle/epilogue v5-verbatim.
//   Boundary (s < w, 6 wave-steps = 3.6%): rows i0+s+21 (<=147) read DIRECT
//   from L2-resident x1T with identical index math (incl. XOR chunk swizzle).
//   Barrier: s_waitcnt vmcnt(7) (keep this step's stage(3)+stores(4) in
//   flight; drains stage issued last step whose deadline is next step) +
//   s_barrier + sched_barrier. s=19: vmcnt(4) (no stage issued; drains row 20,
//   staged at s=18, needed at s=20). s=20: no barrier (kernel end drains).
//   LDS: 3*13,312 + 9,472 = 49,408 B. Grid 512, XCD swizzle as v5.

#define NB 4
#define NC 128
#define NW 128
#define NH 128
#define DW 21
#define PAD 10
#define NROW_T 148   // NW + 2*PAD
#define NCOL_T 160   // padded cols (148..159 zero)
#define NCH 441
#define PS 37        // patch col stride (col-major [16 cols][37 rows]); ~2% conflict cost
#define SCOLS 52     // slice cols: 32 out + 20 halo
#define SUS (SCOLS * NC)        // 6656 ushorts = 13,312 B
#define ROW_US (NCOL_T * NC)    // 20480 ushorts per full x1T row
#define NBUF 3

typedef __attribute__((ext_vector_type(8))) short short8;   // 8 bf16
typedef __attribute__((ext_vector_type(4))) float float4v;  // 4 fp32

__device__ inline ushort f2bf(float f) {
    union { float f; uint u; } v; v.f = f;
    const uint u = v.u;
    return (ushort)((u + 0x7fffu + ((u >> 16) & 1u)) >> 16);  // RNE
}

__device__ inline void async_copy16(const void* g, void* l) {
    __builtin_amdgcn_global_load_lds(
        (const __attribute__((address_space(1))) void*)g,
        (__attribute__((address_space(3))) void*)l, 16, 0, 0);
}

// Stage one 13,312 B row slice: 3 full 4 KB rounds + 1 KB tail (wave 0 only).
// Per-wave VMEM instr count: wave 0 = 4, waves 1-3 = 3 (vmcnt(7) math relies
// on this: stage(3-4) + stores(4) are the newest 7-8 ops at the step barrier).
__device__ inline void stage_row(const ushort* src, ushort* dst, int t) {
    const char* s = (const char*)src;
    char* d = (char*)dst;
    #pragma unroll
    for (int it = 0; it < 3; ++it) {
        const int off = it * 4096 + t * 16;
        async_copy16(s + off, d + off);
    }
    if (t < 64) {
        const int off = 12288 + t * 16;
        async_copy16(s + off, d + off);
    }
}

// One block per (b, padded row r). v5 verbatim.
__global__ __launch_bounds__(256) void transpose_x1(const float* __restrict__ x1,
                                                    ushort* __restrict__ x1T) {
    __shared__ uint tile[128][65];
    const int t = threadIdx.x;
    const int b = blockIdx.x / NROW_T;
    const int r = blockIdx.x % NROW_T;
    const int w = r - PAD;
    const bool inr = (w >= 0 && w < NW);
    if (inr) {
        #pragma unroll
        for (int it = 0; it < 8; ++it) {
            const int u = it * 256 + t;
            const int g4 = u & 31;          // float4 group along h (coalesced)
            const int cp = u >> 5;          // channel pair
            const float4 va = *(const float4*)&x1[(((size_t)b * NC + 2 * cp    ) * NW + w) * NH + g4 * 4];
            const float4 vb = *(const float4*)&x1[(((size_t)b * NC + 2 * cp + 1) * NW + w) * NH + g4 * 4];
            tile[g4 * 4 + 0][cp] = (uint)f2bf(va.x) | ((uint)f2bf(vb.x) << 16);
            tile[g4 * 4 + 1][cp] = (uint)f2bf(va.y) | ((uint)f2bf(vb.y) << 16);
            tile[g4 * 4 + 2][cp] = (uint)f2bf(va.z) | ((uint)f2bf(vb.z) << 16);
            tile[g4 * 4 + 3][cp] = (uint)f2bf(va.w) | ((uint)f2bf(vb.w) << 16);
        }
    }
    __syncthreads();
    #pragma unroll
    for (int it = 0; it < 10; ++it) {
        const int u = it * 256 + t;
        const int cg = u & 15;
        const int col = u >> 4;             // 0..159
        uint4 v = make_uint4(0, 0, 0, 0);
        const int h = col - PAD;
        if (inr && h >= 0 && h < NH) {
            v.x = tile[h][cg * 4 + 0];
            v.y = tile[h][cg * 4 + 1];
            v.z = tile[h][cg * 4 + 2];
            v.w = tile[h][cg * 4 + 3];
        }
        const int chunk = cg ^ (col & 15);  // swizzle for conflict-free pass-2 reads
        *(uint4*)&x1T[(((size_t)b * NROW_T + r) * NCOL_T + col) * NC + chunk * 8] = v;
    }
}

// Block = (b, i-quad, j-quarter), XCD-swizzled, 512 blocks, 2 blocks/CU.
// 256 threads = 4 waves; wave w owns output row i0+w and sweeps di in
// wraparound order (s - w) mod 21.
__global__ __launch_bounds__(256) void corr_mfma(const ushort* __restrict__ x1T,
                                                 const float* __restrict__ x2,
                                                 float* __restrict__ out) {
    __shared__ ushort win[NBUF][SUS];       // 39,936 B rolling row window
    __shared__ float patch[4][16 * PS];     // 9,472 B

    const int t = threadIdx.x;
    const int wave = t >> 6;
    const int lane = t & 63;
    const int n16 = lane & 15;
    const int q = lane >> 4;

    // XCD swizzle: hw XCD = blockIdx%8 -> XCD k serves (b = k>>1, ihalf = k&1);
    // per-XCD x1T band ~3.4 MB < 4 MB L2. 64 slots = 16 i-quads x 4 j-quarters.
    const int n = blockIdx.x;
    const int b = (n & 7) >> 1;
    const int ihalf = n & 1;
    const int slot = n >> 3;                // 0..63
    const int iq = ihalf * 16 + (slot >> 2);
    const int jq = slot & 3;
    const int i0 = iq * 4;
    const int col0 = jq * 32;
    const int i = i0 + wave;                // this wave's output row (fixed)

    const ushort* xbase = x1T + (size_t)(b * NROW_T) * ROW_US + (size_t)col0 * NC;

    // prologue: stage rows i0, i0+1 into buffers 0, 1 (buffer = row-offset % 3)
    stage_row(xbase + (size_t)(i0 + 0) * ROW_US, win[0], t);
    stage_row(xbase + (size_t)(i0 + 1) * ROW_US, win[1], t);

    // B fragments from fp32 x2 (own row; read-once; lane n=n16, k=q*8+e+32*k4)
    short8 Bf[2][4];
    #pragma unroll
    for (int nt = 0; nt < 2; ++nt) {
        const int jc = col0 + nt * 16 + n16;
        #pragma unroll
        for (int k4 = 0; k4 < 4; ++k4) {
            short8 s;
            #pragma unroll
            for (int e = 0; e < 8; ++e) {
                const int c = k4 * 32 + q * 8 + e;
                s[e] = (short)f2bf(x2[(((size_t)b * NC + c) * NW + i) * NH + jc]);
            }
            Bf[nt][k4] = s;
        }
    }

    __syncthreads();  // prologue staging + B loads drained (full drain OK once)

    float* P = &patch[wave][0];

    for (int s = 0; s < 21; ++s) {
        const int di = (s - wave + 21) % 21;   // this wave's di at step s

        // A-fragments: staged row i0+s for s >= wave; else direct L2 read of
        // row i0+s+21 (6 wave-steps/block total; rows <= i0+23 <= 147).
        short8 Af[4][4];
        if (s >= wave) {
            const ushort* A = win[s % NBUF];
            #pragma unroll
            for (int k4 = 0; k4 < 4; ++k4) {
                const int kc = q + 4 * k4;
                #pragma unroll
                for (int tl = 0; tl < 4; ++tl) {
                    const int base = (tl < 3) ? tl * 16 : 36;
                    const int c = base + n16;
                    Af[tl][k4] = *(const short8*)&A[c * NC + ((kc ^ (c & 15)) & 15) * 8];
                }
            }
        } else {
            const ushort* A = xbase + (size_t)(i0 + s + 21) * ROW_US;
            #pragma unroll
            for (int k4 = 0; k4 < 4; ++k4) {
                const int kc = q + 4 * k4;
                #pragma unroll
                for (int tl = 0; tl < 4; ++tl) {
                    const int base = (tl < 3) ? tl * 16 : 36;
                    const int c = base + n16;
                    Af[tl][k4] = *(const short8*)&A[c * NC + ((kc ^ (c & 15)) & 15) * 8];
                }
            }
        }

        // prefetch row i0+s+2 into buffer (s+2)%3: that buffer held row s-1,
        // whose readers all passed the end-of-step-(s-1) barrier. Deadline is
        // step s+2 (two steps of lead) -- the counted vmcnt below keeps it in
        // flight across this step's barrier.
        if (s + 2 <= 20)
            stage_row(xbase + (size_t)(i0 + s + 2) * ROW_US, win[(s + 2) % NBUF], t);

        // Stores must be the newest VMEM ops at the barrier: pin stage/loads
        // before MFMA+epilogue.
        __builtin_amdgcn_sched_barrier(0);

        float4v a00 = {0.f,0.f,0.f,0.f}, a01 = {0.f,0.f,0.f,0.f}, a02 = {0.f,0.f,0.f,0.f};
        float4v a10 = {0.f,0.f,0.f,0.f}, a11 = {0.f,0.f,0.f,0.f}, a12 = {0.f,0.f,0.f,0.f};
        #pragma unroll
        for (int k4 = 0; k4 < 4; ++k4) {
            a00 = __builtin_amdgcn_mfma_f32_16x16x32_bf16(Af[0][k4], Bf[0][k4], a00, 0, 0, 0);
            a01 = __builtin_amdgcn_mfma_f32_16x16x32_bf16(Af[1][k4], Bf[0][k4], a01, 0, 0, 0);
            a02 = __builtin_amdgcn_mfma_f32_16x16x32_bf16(Af[2][k4], Bf[0][k4], a02, 0, 0, 0);
            a10 = __builtin_amdgcn_mfma_f32_16x16x32_bf16(Af[1][k4], Bf[1][k4], a10, 0, 0, 0);
            a11 = __builtin_amdgcn_mfma_f32_16x16x32_bf16(Af[2][k4], Bf[1][k4], a11, 0, 0, 0);
            a12 = __builtin_amdgcn_mfma_f32_16x16x32_bf16(Af[3][k4], Bf[1][k4], a12, 0, 0, 0);
        }

        // Epilogue: per nt, band-extract via per-wave col-major patch P[n*37+r].
        // Exactly 4 global store instrs per wave per step (2 nt x 2 it2).
        #pragma unroll
        for (int nt = 0; nt < 2; ++nt) {
            const float4v va = nt ? a10 : a00;  // rel rows 0..15
            const float4v vb = nt ? a11 : a01;  // rel rows 16..31
            const float4v vc = nt ? a12 : a02;  // nt0 q==0 / nt1 q==3 -> rows 32..35
            #pragma unroll
            for (int reg = 0; reg < 4; ++reg) {
                P[n16 * PS + q * 4 + reg]      = va[reg];
                P[n16 * PS + 16 + q * 4 + reg] = vb[reg];
            }
            if (q == (nt ? 3 : 0)) {
                #pragma unroll
                for (int reg = 0; reg < 4; ++reg)
                    P[n16 * PS + 32 + reg] = vc[reg];
            }
            #pragma unroll
            for (int it2 = 0; it2 < 2; ++it2) {
                const int u = it2 * 64 + lane;
                if (u < 84) {
                    const int dj = u >> 2;
                    const int jj = (u & 3) * 4;
                    float4v v;
                    #pragma unroll
                    for (int p = 0; p < 4; ++p)
                        v[p] = P[(jj + p) * (PS + 1) + dj];  // col jj+p, row jj+p+dj
                    *(float4v*)&out[(((size_t)(b * NCH + di * DW + dj)) * NW + i) * NH
                                    + col0 + nt * 16 + jj] = v;
                }
            }
        }

        // Counted-vmcnt step barrier: keep THIS step's stage (3-4) + stores (4)
        // in flight; drain the stage issued LAST step (its row is read next
        // step). s=19: no stage this step -> vmcnt(4) drains row 20 (staged at
        // s=18, read at s=20). s=20: no barrier; kernel end drains stores.
        if (s < 20) {
            if (s < 19) { asm volatile("s_waitcnt vmcnt(7)" ::: "memory"); }
            else        { asm volatile("s_waitcnt vmcnt(4)" ::: "memory"); }
            __builtin_amdgcn_s_barrier();
            __builtin_amdgcn_sched_barrier(0);
        }
    }
}

extern "C" void kernel_launch(void* const* d_in, const int* in_sizes, int n_in,
                              void* d_out, int out_size, void* d_ws, size_t ws_size,
                              hipStream_t stream) {
    const float* x1 = (const float*)d_in[0];
    const float* x2 = (const float*)d_in[1];
    float* out = (float*)d_out;
    ushort* x1T = (ushort*)d_ws;  // 4*148*160*128*2 = 24,248,320 B
    transpose_x1<<<dim3(NB * NROW_T), dim3(256), 0, stream>>>(x1, x1T);
    corr_mfma<<<dim3(NB * 32 * 4), dim3(256), 0, stream>>>(x1T, x2, out);
}